// Round 1
// baseline (88.393 us; speedup 1.0000x reference)
//
#include <hip/hip_runtime.h>
#include <hip/hip_bf16.h>

// Problem constants (fixed by setup_inputs): emb [4,64,64,64] f32, lab [4,64,64] i32
#define NB    4
#define NPIX  4096   // 64*64
#define CH    64
#define TILE  128
#define TPB   32     // NPIX / TILE tiles per batch
#define PAIRS 528    // TPB*(TPB+1)/2 triangular tile pairs
#define MARGIN 0.5f

typedef __attribute__((ext_vector_type(8))) short   bf16x8;
typedef __attribute__((ext_vector_type(4))) float   f32x4;

// RNE float -> bf16 (bit-level, avoids __hip_bfloat16 ctor issues in unions)
static __device__ inline unsigned short f2bf(float x) {
    unsigned int u = __builtin_bit_cast(unsigned int, x);
    u = (u + 0x7FFFu + ((u >> 16) & 1u)) >> 16;
    return (unsigned short)u;
}

// ---------------- Kernel 1: per-batch label histogram -> per-pixel weight ----
__global__ void prep_kernel(const int* __restrict__ lab, float* __restrict__ pw) {
    __shared__ int hist[16];
    int b = blockIdx.x;
    if (threadIdx.x < 16) hist[threadIdx.x] = 0;
    __syncthreads();
    const int* lb = lab + b * NPIX;
    for (int i = threadIdx.x; i < NPIX; i += 256) atomicAdd(&hist[lb[i]], 1);
    __syncthreads();
    float* pwb = pw + b * NPIX;
    for (int i = threadIdx.x; i < NPIX; i += 256) pwb[i] = 1.0f / (float)hist[lb[i]];
}

// ---------------- Kernel 2: fused Gram tile + pairwise loss epilogue ---------
// One block = one (batch, ti<=tj) 128x128 tile pair. 256 threads = 4 waves (2x2).
__launch_bounds__(256)
__global__ void pair_kernel(const float* __restrict__ emb, const int* __restrict__ lab,
                            const float* __restrict__ pw, float* __restrict__ partials) {
    __shared__ short As[TILE * CH];   // bf16, XOR-swizzled rows (16 KB)
    __shared__ short Bs[TILE * CH];   // 16 KB
    __shared__ int   rlab[TILE], clab[TILE];
    __shared__ float rpw[TILE], cpw[TILE];
    __shared__ float wred[4];

    const int bid = blockIdx.x;
    const int b   = bid / PAIRS;
    int p = bid - b * PAIRS;
    int ti = 0, off = 0;
    while (p >= off + (TPB - ti)) { off += TPB - ti; ++ti; }
    const int tj = ti + (p - off);
    const int rowbase = ti * TILE, colbase = tj * TILE;

    const float* Eb = emb + (size_t)b * NPIX * CH;
    const int t = threadIdx.x;

    // stage label / weight tables
    if (t < TILE) {
        rlab[t] = lab[b * NPIX + rowbase + t];
        rpw[t]  = pw[b * NPIX + rowbase + t];
    } else {
        int u = t - TILE;
        clab[u] = lab[b * NPIX + colbase + u];
        cpw[u]  = pw[b * NPIX + colbase + u];
    }

    // stage A/B tiles: fp32 -> bf16, swizzled LDS writes.
    // thread t handles row = t>>1, half = t&1 (32 floats) of each tile.
    {
        const int row  = t >> 1;
        const int half = t & 1;
        const float* srcA = Eb + (size_t)(rowbase + row) * CH + half * 32;
        const float* srcB = Eb + (size_t)(colbase + row) * CH + half * 32;
        char* AsB = (char*)As;
        char* BsB = (char*)Bs;
        const int sw = (row & 7) << 4;
#pragma unroll
        for (int j = 0; j < 4; ++j) {
            const int boff = row * 128 + ((half * 64 + j * 16) ^ sw);
            {
                f32x4 x0 = *(const f32x4*)(srcA + j * 8);
                f32x4 x1 = *(const f32x4*)(srcA + j * 8 + 4);
                union { bf16x8 v; unsigned short h[8]; } u;
#pragma unroll
                for (int e = 0; e < 4; ++e) { u.h[e] = f2bf(x0[e]); u.h[4 + e] = f2bf(x1[e]); }
                *(bf16x8*)(AsB + boff) = u.v;
            }
            {
                f32x4 x0 = *(const f32x4*)(srcB + j * 8);
                f32x4 x1 = *(const f32x4*)(srcB + j * 8 + 4);
                union { bf16x8 v; unsigned short h[8]; } u;
#pragma unroll
                for (int e = 0; e < 4; ++e) { u.h[e] = f2bf(x0[e]); u.h[4 + e] = f2bf(x1[e]); }
                *(bf16x8*)(BsB + boff) = u.v;
            }
        }
    }
    __syncthreads();

    // MFMA compute: each wave owns a 64x64 output sub-tile
    const int lane = t & 63, wid = t >> 6;
    const int wr = wid >> 1, wc = wid & 1;
    const int lrow = lane & 15, lk = lane >> 4;

    f32x4 acc[4][4];
#pragma unroll
    for (int i = 0; i < 4; ++i)
#pragma unroll
        for (int j = 0; j < 4; ++j) acc[i][j] = (f32x4){0.f, 0.f, 0.f, 0.f};

    const char* AsB = (const char*)As;
    const char* BsB = (const char*)Bs;
#pragma unroll
    for (int kk = 0; kk < 2; ++kk) {
        bf16x8 af[4], bfv[4];
#pragma unroll
        for (int i = 0; i < 4; ++i) {
            const int row = wr * 64 + i * 16 + lrow;
            af[i] = *(const bf16x8*)(AsB + row * 128 + ((kk * 64 + lk * 16) ^ ((row & 7) << 4)));
        }
#pragma unroll
        for (int j = 0; j < 4; ++j) {
            const int row = wc * 64 + j * 16 + lrow;
            bfv[j] = *(const bf16x8*)(BsB + row * 128 + ((kk * 64 + lk * 16) ^ ((row & 7) << 4)));
        }
#pragma unroll
        for (int i = 0; i < 4; ++i)
#pragma unroll
            for (int j = 0; j < 4; ++j)
                acc[i][j] = __builtin_amdgcn_mfma_f32_16x16x32_bf16(af[i], bfv[j], acc[i][j], 0, 0, 0);
    }

    // Epilogue: per_pair = same ? (1-sim) : relu(sim-margin); weighted sum.
    // C/D layout: col = lane&15, row = (lane>>4)*4 + reg  [verified m89]
    float facc = 0.f;
#pragma unroll
    for (int j = 0; j < 4; ++j) {
        const int c = wc * 64 + j * 16 + lrow;
        const int cl = clab[c];
        const float cp = cpw[c];
#pragma unroll
        for (int i = 0; i < 4; ++i) {
#pragma unroll
            for (int r = 0; r < 4; ++r) {
                const int rr = wr * 64 + i * 16 + lk * 4 + r;
                const float sim = acc[i][j][r];
                const float val = (rlab[rr] == cl) ? (1.0f - sim)
                                                   : fmaxf(sim - MARGIN, 0.0f);
                facc = fmaf(rpw[rr] * cp, val, facc);
            }
        }
    }

    // block reduction -> one partial per block (off-diagonal tiles count twice)
#pragma unroll
    for (int o = 32; o > 0; o >>= 1) facc += __shfl_down(facc, o);
    if (lane == 0) wred[wid] = facc;
    __syncthreads();
    if (t == 0) {
        float s = wred[0] + wred[1] + wred[2] + wred[3];
        partials[bid] = s * ((ti == tj) ? 1.0f : 2.0f);
    }
}

// ---------------- Kernel 3: final reduction ---------------------------------
__global__ void reduce_kernel(const float* __restrict__ partials, float* __restrict__ out, int n) {
    float s = 0.f;
    for (int i = threadIdx.x; i < n; i += 256) s += partials[i];
#pragma unroll
    for (int o = 32; o > 0; o >>= 1) s += __shfl_down(s, o);
    __shared__ float wred[4];
    if ((threadIdx.x & 63) == 0) wred[threadIdx.x >> 6] = s;
    __syncthreads();
    if (threadIdx.x == 0) out[0] = (wred[0] + wred[1] + wred[2] + wred[3]) * (float)NPIX;
}

extern "C" void kernel_launch(void* const* d_in, const int* in_sizes, int n_in,
                              void* d_out, int out_size, void* d_ws, size_t ws_size,
                              hipStream_t stream) {
    const float* emb = (const float*)d_in[0];
    const int*   lab = (const int*)d_in[1];
    float* out = (float*)d_out;
    float* pw       = (float*)d_ws;                                     // 4*4096 f32
    float* partials = (float*)((char*)d_ws + NB * NPIX * sizeof(float)); // 2112 f32

    prep_kernel<<<NB, 256, 0, stream>>>(lab, pw);
    pair_kernel<<<NB * PAIRS, 256, 0, stream>>>(emb, lab, pw, partials);
    reduce_kernel<<<1, 256, 0, stream>>>(partials, out, NB * PAIRS);
}